// Round 1
// baseline (77.478 us; speedup 1.0000x reference)
//
#include <hip/hip_runtime.h>

// Single-head causal attention, fused: QKV projection + softmax(QK^T)V.
// B=256 blocks (one per batch), 512 threads (8 waves). All tiles in LDS.
// fp16 MFMA (16x16x32): A frag row=lane&15, k=8*(lane>>4)+i;
//                       B frag col=lane&15, k=8*(lane>>4)+i;
//                       C/D  col=lane&15, row=4*(lane>>4)+reg.

#define B_ 256
#define T_ 256
#define C_ 384
#define H_ 64

typedef __attribute__((ext_vector_type(4))) float     f32x4;
typedef __attribute__((ext_vector_type(8))) _Float16  f16x8;
typedef __attribute__((ext_vector_type(4))) _Float16  f16x4;

#define MFMA16(a, b, c) __builtin_amdgcn_mfma_f32_16x16x32_f16((a), (b), (c), 0, 0, 0)

// LDS layout (units: _Float16). Strides padded +8 to break bank conflicts.
constexpr int SX = 40;            // Xs stride  (32 cols + 8 pad)
constexpr int SW = 40;            // Wt stride
constexpr int SQ = 72;            // Qs/Ks stride (64 + 8)
constexpr int SV = 264;           // Vt stride (256 + 8)
constexpr int SP = 72;            // Ps stride
constexpr int OFF_K = 256 * SQ;               // 18432
constexpr int OFF_V = OFF_K + 256 * SQ;       // 36864
constexpr int OFF_U = OFF_V + 64 * SV;        // 53760 (union: Xs+Wt | Ps)
constexpr int OFF_W = OFF_U + 256 * SX;       // Wt after Xs
constexpr int SMEM_HALFS = OFF_U + 8 * 32 * SP;   // 53760 + 18432 = 72192
constexpr int SMEM_BYTES = SMEM_HALFS * 2;        // 144384 B (<160 KiB)

__global__ __launch_bounds__(512, 2) void head_fused(
    const float* __restrict__ x,
    const float* __restrict__ Wq,
    const float* __restrict__ Wk,
    const float* __restrict__ Wv,
    float* __restrict__ out)
{
    extern __shared__ _Float16 sm[];
    _Float16* Qs = sm;                 // [256][SQ]
    _Float16* Ks = sm + OFF_K;         // [256][SQ]
    _Float16* Vt = sm + OFF_V;         // [64][SV]   (V transposed: Vt[h][s])
    _Float16* Xs = sm + OFF_U;         // [256][SX]  (phase-1 staging)
    _Float16* Wt = sm + OFF_W;         // [3][64][SW] (W transposed: Wt[p][h][kc])
    _Float16* Ps = sm + OFF_U;         // [8][32][SP] (phase-2 per-wave P chunk)

    const int tid  = threadIdx.x;
    const int lane = tid & 63;
    const int wid  = tid >> 6;         // 0..7
    const int lo   = lane & 15;
    const int hi   = lane >> 4;        // 0..3
    const int b    = blockIdx.x;
    const float* xb = x + (size_t)b * (T_ * C_);

    // ---------------- Phase 1: Q,K,V = x @ W{q,k,v} ----------------
    f32x4 acc[3][2][4] = {};   // [proj][row-tile][col-tile], rows 32*wid..+31

    for (int kk = 0; kk < C_; kk += 32) {
        // stage Xs[r][0..31] = fp16(x[b][r][kk+c])  (2048 float4 total)
        #pragma unroll
        for (int i = 0; i < 4; ++i) {
            int idx = tid + i * 512;          // 0..2047
            int r   = idx >> 3;
            int c4  = (idx & 7) * 4;
            float4 xv = *(const float4*)(xb + r * C_ + kk + c4);
            f16x4 hv = { (_Float16)xv.x, (_Float16)xv.y, (_Float16)xv.z, (_Float16)xv.w };
            *(f16x4*)(Xs + r * SX + c4) = hv;
        }
        // stage Wt[p][h][kc] = fp16(W_p[kk+kc][h])
        #pragma unroll
        for (int i = 0; i < 4; ++i) {
            int idx = tid + i * 512;          // 0..2047
            int kc  = idx >> 6;               // 0..31
            int h   = idx & 63;
            Wt[(0 * 64 + h) * SW + kc] = (_Float16)Wq[(kk + kc) * H_ + h];
            Wt[(1 * 64 + h) * SW + kc] = (_Float16)Wk[(kk + kc) * H_ + h];
            Wt[(2 * 64 + h) * SW + kc] = (_Float16)Wv[(kk + kc) * H_ + h];
        }
        __syncthreads();

        f16x8 a0 = *(const f16x8*)(Xs + (32 * wid + lo) * SX + 8 * hi);
        f16x8 a1 = *(const f16x8*)(Xs + (32 * wid + 16 + lo) * SX + 8 * hi);
        #pragma unroll
        for (int p = 0; p < 3; ++p) {
            #pragma unroll
            for (int nt = 0; nt < 4; ++nt) {
                f16x8 bf = *(const f16x8*)(Wt + (p * 64 + nt * 16 + lo) * SW + 8 * hi);
                acc[p][0][nt] = MFMA16(a0, bf, acc[p][0][nt]);
                acc[p][1][nt] = MFMA16(a1, bf, acc[p][1][nt]);
            }
        }
        __syncthreads();
    }

    // write Q (pre-scaled), K, V(transposed) to LDS
    #pragma unroll
    for (int rt = 0; rt < 2; ++rt) {
        #pragma unroll
        for (int nt = 0; nt < 4; ++nt) {
            #pragma unroll
            for (int reg = 0; reg < 4; ++reg) {
                int srow = 32 * wid + 16 * rt + 4 * hi + reg;
                int h    = 16 * nt + lo;
                Qs[srow * SQ + h] = (_Float16)(0.125f * acc[0][rt][nt][reg]);
                Ks[srow * SQ + h] = (_Float16)(acc[1][rt][nt][reg]);
                Vt[h * SV + srow] = (_Float16)(acc[2][rt][nt][reg]);
            }
        }
    }
    __syncthreads();

    // ---------------- Phase 2: S = Q K^T, softmax, O = P V ----------------
    // per wave: rows 32*wid..+31; full 32x256 S in registers (128 VGPR)
    f32x4 sacc[2][16] = {};
    #pragma unroll
    for (int ks = 0; ks < 2; ++ks) {
        f16x8 a0 = *(const f16x8*)(Qs + (32 * wid + lo) * SQ + 32 * ks + 8 * hi);
        f16x8 a1 = *(const f16x8*)(Qs + (32 * wid + 16 + lo) * SQ + 32 * ks + 8 * hi);
        #pragma unroll
        for (int ct = 0; ct < 16; ++ct) {
            f16x8 bf = *(const f16x8*)(Ks + (16 * ct + lo) * SQ + 32 * ks + 8 * hi);
            sacc[0][ct] = MFMA16(a0, bf, sacc[0][ct]);
            sacc[1][ct] = MFMA16(a1, bf, sacc[1][ct]);
        }
    }

    // causal mask + softmax (row lives across a 16-lane group; 4 rows per reg set)
    #pragma unroll
    for (int rt = 0; rt < 2; ++rt) {
        #pragma unroll
        for (int reg = 0; reg < 4; ++reg) {
            const int rowg = 32 * wid + 16 * rt + 4 * hi + reg;
            float m = -1e30f;
            #pragma unroll
            for (int ct = 0; ct < 16; ++ct) {
                float v = sacc[rt][ct][reg];
                v = (16 * ct + lo <= rowg) ? v : -1e30f;
                sacc[rt][ct][reg] = v;
                m = fmaxf(m, v);
            }
            #pragma unroll
            for (int s = 1; s < 16; s <<= 1) m = fmaxf(m, __shfl_xor(m, s, 16));
            float l = 0.f;
            #pragma unroll
            for (int ct = 0; ct < 16; ++ct) {
                float v = sacc[rt][ct][reg];
                float p = (v > -1e29f) ? __expf(v - m) : 0.f;
                sacc[rt][ct][reg] = p;
                l += p;
            }
            #pragma unroll
            for (int s = 1; s < 16; s <<= 1) l += __shfl_xor(l, s, 16);
            float rinv = 1.f / l;
            #pragma unroll
            for (int ct = 0; ct < 16; ++ct) sacc[rt][ct][reg] *= rinv;
        }
    }

    // O = P @ V, bouncing P through per-wave LDS chunk (layout conversion)
    f32x4 oacc[2][4] = {};
    _Float16* Pw = Ps + wid * 32 * SP;
    #pragma unroll
    for (int kc = 0; kc < 4; ++kc) {
        #pragma unroll
        for (int rt = 0; rt < 2; ++rt) {
            #pragma unroll
            for (int c = 0; c < 4; ++c) {
                #pragma unroll
                for (int reg = 0; reg < 4; ++reg) {
                    Pw[(16 * rt + 4 * hi + reg) * SP + c * 16 + lo] =
                        (_Float16)sacc[rt][4 * kc + c][reg];
                }
            }
        }
        asm volatile("s_waitcnt lgkmcnt(0)" ::: "memory");   // wave-local write->read

        #pragma unroll
        for (int ks = 0; ks < 2; ++ks) {
            f16x8 a0 = *(const f16x8*)(Pw + lo * SP + 32 * ks + 8 * hi);
            f16x8 a1 = *(const f16x8*)(Pw + (16 + lo) * SP + 32 * ks + 8 * hi);
            #pragma unroll
            for (int ht = 0; ht < 4; ++ht) {
                f16x8 bv = *(const f16x8*)(Vt + (16 * ht + lo) * SV + 64 * kc + 32 * ks + 8 * hi);
                oacc[0][ht] = MFMA16(a0, bv, oacc[0][ht]);
                oacc[1][ht] = MFMA16(a1, bv, oacc[1][ht]);
            }
        }
        asm volatile("s_waitcnt lgkmcnt(0)" ::: "memory");   // reads done before next writes
    }

    // store O (fp32)
    float* ob = out + (size_t)b * (T_ * H_);
    #pragma unroll
    for (int rt = 0; rt < 2; ++rt) {
        #pragma unroll
        for (int ht = 0; ht < 4; ++ht) {
            #pragma unroll
            for (int reg = 0; reg < 4; ++reg) {
                int t = 32 * wid + 16 * rt + 4 * hi + reg;
                ob[t * H_ + 16 * ht + lo] = oacc[rt][ht][reg];
            }
        }
    }
}

extern "C" void kernel_launch(void* const* d_in, const int* in_sizes, int n_in,
                              void* d_out, int out_size, void* d_ws, size_t ws_size,
                              hipStream_t stream) {
    const float* x  = (const float*)d_in[0];
    const float* Wq = (const float*)d_in[1];
    const float* Wk = (const float*)d_in[2];
    const float* Wv = (const float*)d_in[3];
    float* out = (float*)d_out;

    (void)d_ws; (void)ws_size; (void)in_sizes; (void)n_in; (void)out_size;

    hipFuncSetAttribute(reinterpret_cast<const void*>(head_fused),
                        hipFuncAttributeMaxDynamicSharedMemorySize, SMEM_BYTES);
    head_fused<<<dim3(B_), dim3(512), SMEM_BYTES, stream>>>(x, Wq, Wk, Wv, out);
}